// Round 13
// baseline (226.920 us; speedup 1.0000x reference)
//
#include <hip/hip_runtime.h>
#include <stdint.h>

typedef uint16_t u16;
typedef uint32_t u32;
typedef __bf16 bf16_t;
typedef __bf16 bf16x8 __attribute__((ext_vector_type(8)));
typedef float  f32x4  __attribute__((ext_vector_type(4)));

#define MFMA16(a,b,c) __builtin_amdgcn_mfma_f32_16x16x32_bf16(a,b,c,0,0,0)

static __device__ __forceinline__ u16 f2bf(float f){
  union { bf16_t b; u16 u; } cv; cv.b = (bf16_t)f; return cv.u;
}
static __device__ __forceinline__ u32 pack2(float a, float b){
  return (u32)f2bf(a) | ((u32)f2bf(b) << 16);
}

// ---------------- K1: fused Q/K/V projection + (y==3) bias-table blocks. ------------------
// C[8192,256] = X @ W^T + b (f32 in, bf16 MFMA, bf16 out), reg-prefetch double-buffered.
// Wsh/Cs union keeps LDS at 35.8KB -> 3 blocks/CU resident in one dispatch round.
__global__ __attribute__((amdgpu_waves_per_eu(3, 3))) __launch_bounds__(256) void k_proj3b(
    const float* __restrict__ X,
    const float* __restrict__ Wq, const float* __restrict__ Bq,
    const float* __restrict__ Wk, const float* __restrict__ Bk,
    const float* __restrict__ Wv, const float* __restrict__ Bvv,
    u16* __restrict__ Qo, u16* __restrict__ Ko, u16* __restrict__ Vo,
    float qscale,
    const float* __restrict__ dist_bias, const float* __restrict__ dir_bias,
    float* __restrict__ ebtab)
{
  if (blockIdx.y == 3){
    int tid = blockIdx.x*256 + threadIdx.x;
    if (blockIdx.x >= 16 || tid >= 63*63) return;
    int dhi = tid / 63, dwi = tid % 63;
    int dh = dhi - 31, dw = dwi - 31;
    int dist = (int)sqrtf((float)(dh*dh + dw*dw));
    if (dist > 59) dist = 59;
    int dir;
    if (dh==0 && dw==0)      dir = 0;
    else if (dh==0)          dir = (dw>0) ? 8  : 0;
    else if (dw==0)          dir = (dh>0) ? 12 : 4;
    else if (dh==dw)         dir = (dh>0) ? 10 : 2;
    else if (dh==-dw)        dir = (dh>0) ? 14 : 6;
    else {
      float ang = atan2f((float)dh, (float)dw) + 3.14159265358979323846f;
      int k = (int)floorf(ang * 2.5464790894703254f);
      dir = k & 15;
    }
    for (int h=0; h<8; h++){
      ebtab[dhi*512 + h*64 + dwi] = expf(dist_bias[dist*8+h] + dir_bias[dir*8+h]);
    }
    return;
  }

  const float* W; const float* Bv; u16* Out; float scale; int vt_mode;
  if (blockIdx.y == 0)      { W = Wq; Bv = Bq;  Out = Qo; scale = qscale; vt_mode = 0; }
  else if (blockIdx.y == 1) { W = Wk; Bv = Bk;  Out = Ko; scale = 1.0f;   vt_mode = 0; }
  else                      { W = Wv; Bv = Bvv; Out = Vo; scale = 1.0f;   vt_mode = 1; }

  __shared__ bf16_t Xs[32*40];
  __shared__ __align__(16) char UU[33280];   // union: Wsh bf16[256*40]=20480B | Cs f32[32*260]=33280B
  bf16_t* Wsh = (bf16_t*)UU;
  float*  Cs  = (float*)UU;
  const int t = threadIdx.x;
  const int wv = t>>6, ln = t&15, qd = (t&63)>>4;
  const int wm = wv & 1, wn = wv >> 1;
  const int m0 = blockIdx.x * 32;

  f32x4 z4 = {0.0f,0.0f,0.0f,0.0f};
  f32x4 acc[8];
  #pragma unroll
  for (int i=0;i<8;i++) acc[i] = z4;

  f32x4 XR; f32x4 WR[8];
  XR = *(const f32x4*)(X + (size_t)(m0 + (t>>3))*256 + (t&7)*4);
  #pragma unroll
  for (int j=0;j<8;j++)
    WR[j] = *(const f32x4*)(W + (size_t)((t>>3)+32*j)*256 + (t&7)*4);

  for (int kt=0; kt<8; kt++){
    __syncthreads();
    { int m = t>>3, k0 = (t&7)*4;
      uint2 pk; pk.x = pack2(XR[0], XR[1]); pk.y = pack2(XR[2], XR[3]);
      *(uint2*)&Xs[m*40 + k0] = pk;
    }
    #pragma unroll
    for (int j=0;j<8;j++){
      int n = (t>>3) + 32*j, k0 = (t&7)*4;
      uint2 pk; pk.x = pack2(WR[j][0], WR[j][1]); pk.y = pack2(WR[j][2], WR[j][3]);
      *(uint2*)&Wsh[n*40 + k0] = pk;
    }
    __syncthreads();
    if (kt < 7){
      XR = *(const f32x4*)(X + (size_t)(m0 + (t>>3))*256 + (kt+1)*32 + (t&7)*4);
      #pragma unroll
      for (int j=0;j<8;j++)
        WR[j] = *(const f32x4*)(W + (size_t)((t>>3)+32*j)*256 + (kt+1)*32 + (t&7)*4);
    }
    bf16x8 a = *(const bf16x8*)&Xs[(wm*16+ln)*40 + qd*8];
    #pragma unroll
    for (int ni=0;ni<8;ni++){
      bf16x8 bb = *(const bf16x8*)&Wsh[(wn*128 + ni*16 + ln)*40 + qd*8];
      acc[ni] = MFMA16(a, bb, acc[ni]);
    }
  }
  __syncthreads();   // Wsh dead after this point; Cs takes over the union
  #pragma unroll
  for (int ni=0;ni<8;ni++){
    const int col = wn*128 + ni*16 + ln;
    const float bias = Bv[col];
    #pragma unroll
    for (int r=0;r<4;r++){
      Cs[(wm*16 + qd*4 + r)*260 + col] = (acc[ni][r] + bias) * scale;
    }
  }
  __syncthreads();
  if (!vt_mode){
    int row = t>>3, c0 = (t&7)*32;
    u16* op = Out + (size_t)(m0+row)*256 + c0;
    #pragma unroll
    for (int i=0;i<4;i++){
      f32x4 v0 = *(const f32x4*)&Cs[row*260 + c0 + i*8];
      f32x4 v1 = *(const f32x4*)&Cs[row*260 + c0 + i*8 + 4];
      union { u16 h[8]; uint4 v; } pk;
      #pragma unroll
      for (int e=0;e<4;e++){ pk.h[e] = f2bf(v0[e]); pk.h[4+e] = f2bf(v1[e]); }
      *(uint4*)(op + i*8) = pk.v;
    }
  } else {
    const int n = t;
    const int b = m0 >> 10, s0 = m0 & 1023;
    u16* op = Out + (size_t)(b*256 + n)*1024 + s0;
    #pragma unroll
    for (int i=0;i<4;i++){
      union { u16 h[8]; uint4 v; } pk;
      #pragma unroll
      for (int e=0;e<8;e++) pk.h[e] = f2bf(Cs[(i*8+e)*260 + n]);
      *(uint4*)(op + i*8) = pk.v;
    }
  }
}

// ---------------- K2a: attention ctx pass: one head per block, kt-range per wave. ---------
// Grid (64 qt, 8 b, 8 h) = 4096 blocks; wave wv owns kt in [wv*8, wv*8+8). Cross-wave
// combine in LDS (2 barriers). (4,4) restored (r12: (4,8) raised occupancy 39->63% but
// HURT dur 69.9->74.5 — occupancy is NOT the binding constraint; VGPR squeeze cost ILP).
// CHANGE vs r9: bias gather via DIRECT L1 loads from the ebtab row instead of
// cE-load + 16 ds_bpermute (__shfl). The ebv loads depend only on loop indices (not on
// the MFMA result), so they issue at loop top and complete under the MFMA — removing
// vmcnt(cE)+lgkmcnt(bpermute) from the QK->exp->bias->Ps critical chain. 16-lane groups
// read 64B contiguous windows of the 256B row (L1-hot).
__global__ __attribute__((amdgpu_waves_per_eu(4, 4))) __launch_bounds__(256) void k_attn_ctx(
    const u16* __restrict__ Qg, const u16* __restrict__ Kg,
    const u16* __restrict__ Vtg, const float* __restrict__ ebtab,
    u16* __restrict__ ctx, float* __restrict__ sden)
{
  __shared__ bf16_t Ps[4][16*40];          // 5120 B, wave-private transpose buffer
  __shared__ float  red[2][4][16];         // 512 B: se/sb per wave per row
  __shared__ float  invb[16];              // 64 B
  __shared__ float  opl[4][16][33];        // 8448 B (pad 33: no 4-way bank alias)

  const int t  = threadIdx.x;
  const int wv = t >> 6;
  const int ln = t & 15;
  const int qd = (t & 63) >> 4;
  const int b  = blockIdx.y;
  const int qt = blockIdx.x;
  const int h  = blockIdx.z;
  const int kt0 = wv*8;
  const int qh_img = qt >> 1;
  const int qw0 = (qt & 1) * 16;

  const u16* Qb  = Qg  + (size_t)(b*1024 + qt*16) * 256;
  const u16* Kb  = Kg  + (size_t)b * 1024 * 256;
  const u16* Vtb = Vtg + (size_t)b * 256 * 1024;

  f32x4 z4 = {0.0f,0.0f,0.0f,0.0f};

  bf16x8 aq = *(const bf16x8*)(Qb + ln*256 + h*32 + qd*8);

  float se[4] = {0,0,0,0}, sb[4] = {0,0,0,0};
  f32x4 oacc[2]; oacc[0]=z4; oacc[1]=z4;

  // lane-constant part of the ebv index: ln - qw0 - qd*4 + 31  (r and kh added below)
  const int ebase = ln - qw0 - qd*4 + 31;

  for (int kti=0; kti<8; kti++){
    const int kt = kt0 + kti;
    const float* ebrow = ebtab + (size_t)(kt - qh_img + 31)*512 + h*64;

    #pragma unroll
    for (int kh=0;kh<2;kh++){
      bf16x8 bk = *(const bf16x8*)(Kb + (size_t)(kt*32 + kh*16 + ln)*256 + h*32 + qd*8);
      f32x4 sc = MFMA16(aq, bk, z4);
      #pragma unroll
      for (int r=0;r<4;r++){
        float e  = exp2f(sc[r]);                 // Q pre-scaled by log2e/sqrt(dk)
        float ebv = ebrow[ebase + kh*16 - r];    // dw+31 in [0,62], L1-hot row
        float eb = e * ebv;
        se[r] += e;
        sb[r] += eb;
        Ps[wv][(qd*4+r)*40 + kh*16 + ln] = (bf16_t)eb;   // unnormalized
      }
    }
    // per-wave in-order LDS + alias-visible dependence orders Ps write->read
    bf16x8 ap = *(const bf16x8*)&Ps[wv][ln*40 + qd*8];
    #pragma unroll
    for (int nh=0;nh<2;nh++){
      bf16x8 bv = *(const bf16x8*)(Vtb + (size_t)(h*32 + nh*16 + ln)*1024 + kt*32 + qd*8);
      oacc[nh] = MFMA16(ap, bv, oacc[nh]);
    }
  }

  // reduce partial denominator sums across the 16 column-lanes (same qd group)
  #pragma unroll
  for (int r=0;r<4;r++){
    #pragma unroll
    for (int m=1;m<16;m<<=1){
      se[r] += __shfl_xor(se[r], m, 16);
      sb[r] += __shfl_xor(sb[r], m, 16);
    }
  }
  if (ln == 0){
    #pragma unroll
    for (int r=0;r<4;r++){
      red[0][wv][qd*4+r] = se[r];
      red[1][wv][qd*4+r] = sb[r];
    }
  }
  // stage this wave's PV partial
  #pragma unroll
  for (int nh=0;nh<2;nh++)
    #pragma unroll
    for (int r=0;r<4;r++)
      opl[wv][qd*4+r][nh*16+ln] = oacc[nh][r];
  __syncthreads();

  if (t < 16){
    float s = red[0][0][t] + red[0][1][t] + red[0][2][t] + red[0][3][t];
    float bsum = red[1][0][t] + red[1][1][t] + red[1][2][t] + red[1][3][t];
    sden[(size_t)(b*8 + h)*1024 + qt*16 + t] = 1.0f / s;
    invb[t] = 1.0f / bsum;
  }
  __syncthreads();

  { // 256 threads: 16 rows x 32 cols, 2 cols/thread -> ctx bf16
    const int row = t >> 4, c = (t & 15)*2;
    float o0 = opl[0][row][c]   + opl[1][row][c]   + opl[2][row][c]   + opl[3][row][c];
    float o1 = opl[0][row][c+1] + opl[1][row][c+1] + opl[2][row][c+1] + opl[3][row][c+1];
    float iv = invb[row];
    *(u32*)(ctx + (size_t)(b*1024 + qt*16 + row)*256 + h*32 + c) = pack2(o0*iv, o1*iv);
  }
}

// ---------------- K2b: attn_w pass. kt-parallel, grid (64,8,4) = 2048 blocks. ------------
// Q fragments for all 8 heads hoisted out of the head loop (32 VGPR) -> 32 independent
// MFMA/exp2 streams per wave; (4,4) gives the allocator the 128-reg budget for it.
__global__ __attribute__((amdgpu_waves_per_eu(4, 4))) __launch_bounds__(256) void k_attn_aw(
    const u16* __restrict__ Qg, const u16* __restrict__ Kg,
    const float* __restrict__ sden, float* __restrict__ AW)
{
  const int t  = threadIdx.x;
  const int wv = t >> 6;
  const int ln = t & 15;
  const int qd = (t & 63) >> 4;
  const int b  = blockIdx.y;
  const int qt = blockIdx.x;
  const int kt0 = blockIdx.z*8 + wv*2;

  const u16* Qb = Qg + (size_t)(b*1024 + qt*16) * 256;
  const u16* Kb = Kg + (size_t)b * 1024 * 256;

  f32x4 z4 = {0.0f,0.0f,0.0f,0.0f};

  bf16x8 aqh[8];
  #pragma unroll
  for (int h=0;h<8;h++)
    aqh[h] = *(const bf16x8*)(Qb + ln*256 + h*32 + qd*8);

  float aw0[2][2][4];
  #pragma unroll
  for (int k2=0;k2<2;k2++)
    #pragma unroll
    for (int kh=0;kh<2;kh++)
      #pragma unroll
      for (int r=0;r<4;r++) aw0[k2][kh][r] = 0.0f;

  #pragma unroll
  for (int h=0;h<8;h++){
    float iv[4];
    #pragma unroll
    for (int r=0;r<4;r++)
      iv[r] = sden[(size_t)(b*8 + h)*1024 + qt*16 + qd*4 + r];
    #pragma unroll
    for (int k2=0;k2<2;k2++){
      #pragma unroll
      for (int kh=0;kh<2;kh++){
        bf16x8 bk = *(const bf16x8*)(Kb + (size_t)((kt0+k2)*32 + kh*16 + ln)*256 + h*32 + qd*8);
        f32x4 sc = MFMA16(aqh[h], bk, z4);
        #pragma unroll
        for (int r=0;r<4;r++)
          aw0[k2][kh][r] += exp2f(sc[r]) * iv[r];
      }
    }
  }
  #pragma unroll
  for (int k2=0;k2<2;k2++)
    #pragma unroll
    for (int kh=0;kh<2;kh++)
      #pragma unroll
      for (int r=0;r<4;r++)
        AW[(size_t)(b*1024 + qt*16 + qd*4 + r)*1024 + (kt0+k2)*32 + kh*16 + ln]
            = aw0[k2][kh][r] * 0.125f;
}

// ---------------- K3: out = ctx@Wo^T + bo ; y = LN(out + x). f32 out. ---------------------
// 16-row blocks: grid 512 = 2 blocks/CU. Wave wv owns cols [wv*64, wv*64+64).
// Wsh/Ys LDS union -> 22.3KB/block.
__global__ __attribute__((amdgpu_waves_per_eu(2, 2))) __launch_bounds__(256) void k_outln(
    const u16* __restrict__ CX, const float* __restrict__ Wo,
    const float* __restrict__ bo, const float* __restrict__ xs,
    const float* __restrict__ lgm, const float* __restrict__ lbt,
    float* __restrict__ Out)
{
  __shared__ bf16_t Cts[16*40];
  __shared__ __align__(16) char UU[20480];   // union: Wsh bf16[256*40] | Ys f32[16*260]=16640B
  bf16_t* Wsh = (bf16_t*)UU;
  float*  Ys  = (float*)UU;
  __shared__ float  parts[4][16][2];
  const int t = threadIdx.x;
  const int wv = t>>6, ln = t&15, qd = (t&63)>>4;
  const int m0 = blockIdx.x * 16;

  f32x4 z4 = {0.0f,0.0f,0.0f,0.0f};
  f32x4 acc[4];
  #pragma unroll
  for (int i=0;i<4;i++) acc[i] = z4;

  u32 CR; f32x4 WR[8];
  CR = *(const u32*)(CX + (size_t)(m0 + (t>>4))*256 + (t&15)*2);
  #pragma unroll
  for (int j=0;j<8;j++)
    WR[j] = *(const f32x4*)(Wo + (size_t)((t>>3)+32*j)*256 + (t&7)*4);

  for (int kt=0; kt<8; kt++){
    __syncthreads();
    *(u32*)&Cts[(t>>4)*40 + (t&15)*2] = CR;
    #pragma unroll
    for (int j=0;j<8;j++){
      int n = (t>>3) + 32*j, k0 = (t&7)*4;
      uint2 pk; pk.x = pack2(WR[j][0], WR[j][1]); pk.y = pack2(WR[j][2], WR[j][3]);
      *(uint2*)&Wsh[n*40 + k0] = pk;
    }
    __syncthreads();
    if (kt < 7){
      CR = *(const u32*)(CX + (size_t)(m0 + (t>>4))*256 + (kt+1)*32 + (t&15)*2);
      #pragma unroll
      for (int j=0;j<8;j++)
        WR[j] = *(const f32x4*)(Wo + (size_t)((t>>3)+32*j)*256 + (kt+1)*32 + (t&7)*4);
    }
    bf16x8 a = *(const bf16x8*)&Cts[ln*40 + qd*8];
    #pragma unroll
    for (int ni=0;ni<4;ni++){
      bf16x8 bb = *(const bf16x8*)&Wsh[(wv*64 + ni*16 + ln)*40 + qd*8];
      acc[ni] = MFMA16(a, bb, acc[ni]);
    }
  }

  float psum[4]={0,0,0,0}, psq[4]={0,0,0,0};
  #pragma unroll
  for (int ni=0;ni<4;ni++){
    const int col = wv*64 + ni*16 + ln;
    const float bias = bo[col];
    #pragma unroll
    for (int r=0;r<4;r++){
      const int row = qd*4 + r;
      float y = acc[ni][r] + bias + xs[(size_t)(m0+row)*256 + col];
      acc[ni][r] = y;
      psum[r] += y; psq[r] += y*y;
    }
  }
  #pragma unroll
  for (int r=0;r<4;r++){
    float a1 = psum[r], a2 = psq[r];
    #pragma unroll
    for (int m=1;m<16;m<<=1){ a1 += __shfl_xor(a1,m,16); a2 += __shfl_xor(a2,m,16); }
    if (ln == 0){
      parts[wv][qd*4 + r][0] = a1;
      parts[wv][qd*4 + r][1] = a2;
    }
  }
  __syncthreads();   // also: all Wsh reads done -> Ys may take over the union
  #pragma unroll
  for (int r=0;r<4;r++){
    const int row = qd*4 + r;
    float s1 = parts[0][row][0] + parts[1][row][0] + parts[2][row][0] + parts[3][row][0];
    float s2 = parts[0][row][1] + parts[1][row][1] + parts[2][row][1] + parts[3][row][1];
    float mu  = s1 * 0.00390625f;
    float var = s2 * 0.00390625f - mu*mu;
    float rs = rsqrtf(var + 1e-5f);
    #pragma unroll
    for (int ni=0;ni<4;ni++){
      const int col = wv*64 + ni*16 + ln;
      Ys[row*260 + col] = (acc[ni][r] - mu)*rs*lgm[col] + lbt[col];
    }
  }
  __syncthreads();
  { int row = t>>4, c0 = (t&15)*16;
    float* op = Out + (size_t)(m0+row)*256 + c0;
    #pragma unroll
    for (int i=0;i<4;i++)
      *(f32x4*)(op + 4*i) = *(const f32x4*)&Ys[row*260 + c0 + 4*i];
  }
}

// -----------------------------------------------------------------------------------------
extern "C" void kernel_launch(void* const* d_in, const int* in_sizes, int n_in,
                              void* d_out, int out_size, void* d_ws, size_t ws_size,
                              hipStream_t stream)
{
  const float* x   = (const float*)d_in[0];
  const float* wq  = (const float*)d_in[1];
  const float* bq  = (const float*)d_in[2];
  const float* wk  = (const float*)d_in[3];
  const float* bk  = (const float*)d_in[4];
  const float* wv_ = (const float*)d_in[5];
  const float* bv  = (const float*)d_in[6];
  const float* wo  = (const float*)d_in[7];
  const float* bo  = (const float*)d_in[8];
  const float* lng = (const float*)d_in[9];
  const float* lnb = (const float*)d_in[10];
  const float* dib = (const float*)d_in[11];
  const float* drb = (const float*)d_in[12];

  // ws: ebtab 128K | CX bf16 4MB | Vt bf16 4MB | sden f32 256K = 8.63 MB.
  // d_out f32: y [0, 8MB) ; attn_w [8MB, 41.5MB).
  //   Q bf16 at y [0,4M), K bf16 at y [4M,8M) -> dead before k_outln writes y.
  char*  ws    = (char*)d_ws;
  float* ebtab = (float*)ws;
  u16*   CX    = (u16*)(ws + 131072);
  u16*   Vt    = (u16*)(ws + 131072 + 4194304);
  float* sden  = (float*)(ws + 131072 + 8388608);
  float* y     = (float*)d_out;
  float* aw    = y + 2097152;
  u16*   Q     = (u16*)y;
  u16*   K     = (u16*)((char*)y + 4194304);

  const float qscale = 0.25503486f;   // log2(e)/sqrt(32) folded into Q

  k_proj3b<<<dim3(256, 4), 256, 0, stream>>>(x, wq, bq, wk, bk, wv_, bv, Q, K, Vt,
                                             qscale, dib, drb, ebtab);
  k_attn_ctx<<<dim3(64, 8, 8), 256, 0, stream>>>(Q, K, Vt, ebtab, CX, sden);
  k_attn_aw<<<dim3(64, 8, 4), 256, 0, stream>>>(Q, K, sden, aw);
  k_outln<<<512, 256, 0, stream>>>(CX, wo, bo, x, lng, lnb, y);
}

// Round 14
// 216.692 us; speedup vs baseline: 1.0472x; 1.0472x over previous
//
#include <hip/hip_runtime.h>
#include <stdint.h>

typedef uint16_t u16;
typedef uint32_t u32;
typedef __bf16 bf16_t;
typedef __bf16 bf16x8 __attribute__((ext_vector_type(8)));
typedef float  f32x4  __attribute__((ext_vector_type(4)));

#define MFMA16(a,b,c) __builtin_amdgcn_mfma_f32_16x16x32_bf16(a,b,c,0,0,0)

static __device__ __forceinline__ u16 f2bf(float f){
  union { bf16_t b; u16 u; } cv; cv.b = (bf16_t)f; return cv.u;
}
static __device__ __forceinline__ u32 pack2(float a, float b){
  return (u32)f2bf(a) | ((u32)f2bf(b) << 16);
}

// ---------------- K1: fused Q/K/V projection + (y==3) bias-table blocks. ------------------
// C[8192,256] = X @ W^T + b (f32 in, bf16 MFMA, bf16 out), reg-prefetch double-buffered.
// Wsh/Cs union keeps LDS at 35.8KB -> 3 blocks/CU resident in one dispatch round.
__global__ __attribute__((amdgpu_waves_per_eu(3, 3))) __launch_bounds__(256) void k_proj3b(
    const float* __restrict__ X,
    const float* __restrict__ Wq, const float* __restrict__ Bq,
    const float* __restrict__ Wk, const float* __restrict__ Bk,
    const float* __restrict__ Wv, const float* __restrict__ Bvv,
    u16* __restrict__ Qo, u16* __restrict__ Ko, u16* __restrict__ Vo,
    float qscale,
    const float* __restrict__ dist_bias, const float* __restrict__ dir_bias,
    float* __restrict__ ebtab)
{
  if (blockIdx.y == 3){
    int tid = blockIdx.x*256 + threadIdx.x;
    if (blockIdx.x >= 16 || tid >= 63*63) return;
    int dhi = tid / 63, dwi = tid % 63;
    int dh = dhi - 31, dw = dwi - 31;
    int dist = (int)sqrtf((float)(dh*dh + dw*dw));
    if (dist > 59) dist = 59;
    int dir;
    if (dh==0 && dw==0)      dir = 0;
    else if (dh==0)          dir = (dw>0) ? 8  : 0;
    else if (dw==0)          dir = (dh>0) ? 12 : 4;
    else if (dh==dw)         dir = (dh>0) ? 10 : 2;
    else if (dh==-dw)        dir = (dh>0) ? 14 : 6;
    else {
      float ang = atan2f((float)dh, (float)dw) + 3.14159265358979323846f;
      int k = (int)floorf(ang * 2.5464790894703254f);
      dir = k & 15;
    }
    for (int h=0; h<8; h++){
      ebtab[dhi*512 + h*64 + dwi] = expf(dist_bias[dist*8+h] + dir_bias[dir*8+h]);
    }
    return;
  }

  const float* W; const float* Bv; u16* Out; float scale; int vt_mode;
  if (blockIdx.y == 0)      { W = Wq; Bv = Bq;  Out = Qo; scale = qscale; vt_mode = 0; }
  else if (blockIdx.y == 1) { W = Wk; Bv = Bk;  Out = Ko; scale = 1.0f;   vt_mode = 0; }
  else                      { W = Wv; Bv = Bvv; Out = Vo; scale = 1.0f;   vt_mode = 1; }

  __shared__ bf16_t Xs[32*40];
  __shared__ __align__(16) char UU[33280];   // union: Wsh bf16[256*40]=20480B | Cs f32[32*260]=33280B
  bf16_t* Wsh = (bf16_t*)UU;
  float*  Cs  = (float*)UU;
  const int t = threadIdx.x;
  const int wv = t>>6, ln = t&15, qd = (t&63)>>4;
  const int wm = wv & 1, wn = wv >> 1;
  const int m0 = blockIdx.x * 32;

  f32x4 z4 = {0.0f,0.0f,0.0f,0.0f};
  f32x4 acc[8];
  #pragma unroll
  for (int i=0;i<8;i++) acc[i] = z4;

  f32x4 XR; f32x4 WR[8];
  XR = *(const f32x4*)(X + (size_t)(m0 + (t>>3))*256 + (t&7)*4);
  #pragma unroll
  for (int j=0;j<8;j++)
    WR[j] = *(const f32x4*)(W + (size_t)((t>>3)+32*j)*256 + (t&7)*4);

  for (int kt=0; kt<8; kt++){
    __syncthreads();
    { int m = t>>3, k0 = (t&7)*4;
      uint2 pk; pk.x = pack2(XR[0], XR[1]); pk.y = pack2(XR[2], XR[3]);
      *(uint2*)&Xs[m*40 + k0] = pk;
    }
    #pragma unroll
    for (int j=0;j<8;j++){
      int n = (t>>3) + 32*j, k0 = (t&7)*4;
      uint2 pk; pk.x = pack2(WR[j][0], WR[j][1]); pk.y = pack2(WR[j][2], WR[j][3]);
      *(uint2*)&Wsh[n*40 + k0] = pk;
    }
    __syncthreads();
    if (kt < 7){
      XR = *(const f32x4*)(X + (size_t)(m0 + (t>>3))*256 + (kt+1)*32 + (t&7)*4);
      #pragma unroll
      for (int j=0;j<8;j++)
        WR[j] = *(const f32x4*)(W + (size_t)((t>>3)+32*j)*256 + (kt+1)*32 + (t&7)*4);
    }
    bf16x8 a = *(const bf16x8*)&Xs[(wm*16+ln)*40 + qd*8];
    #pragma unroll
    for (int ni=0;ni<8;ni++){
      bf16x8 bb = *(const bf16x8*)&Wsh[(wn*128 + ni*16 + ln)*40 + qd*8];
      acc[ni] = MFMA16(a, bb, acc[ni]);
    }
  }
  __syncthreads();   // Wsh dead after this point; Cs takes over the union
  #pragma unroll
  for (int ni=0;ni<8;ni++){
    const int col = wn*128 + ni*16 + ln;
    const float bias = Bv[col];
    #pragma unroll
    for (int r=0;r<4;r++){
      Cs[(wm*16 + qd*4 + r)*260 + col] = (acc[ni][r] + bias) * scale;
    }
  }
  __syncthreads();
  if (!vt_mode){
    int row = t>>3, c0 = (t&7)*32;
    u16* op = Out + (size_t)(m0+row)*256 + c0;
    #pragma unroll
    for (int i=0;i<4;i++){
      f32x4 v0 = *(const f32x4*)&Cs[row*260 + c0 + i*8];
      f32x4 v1 = *(const f32x4*)&Cs[row*260 + c0 + i*8 + 4];
      union { u16 h[8]; uint4 v; } pk;
      #pragma unroll
      for (int e=0;e<4;e++){ pk.h[e] = f2bf(v0[e]); pk.h[4+e] = f2bf(v1[e]); }
      *(uint4*)(op + i*8) = pk.v;
    }
  } else {
    const int n = t;
    const int b = m0 >> 10, s0 = m0 & 1023;
    u16* op = Out + (size_t)(b*256 + n)*1024 + s0;
    #pragma unroll
    for (int i=0;i<4;i++){
      union { u16 h[8]; uint4 v; } pk;
      #pragma unroll
      for (int e=0;e<8;e++) pk.h[e] = f2bf(Cs[(i*8+e)*260 + n]);
      *(uint4*)(op + i*8) = pk.v;
    }
  }
}

// ---------------- K2: fused attention (r5 verbatim, measured 110.4us). --------------------
// No LDS staging (K/V L2-resident); pass 1 barrier-free with named-register prefetch;
// pass 2: one invTab exchange, then wave owns a kt-range, head-sum in-register.
__global__ __attribute__((amdgpu_waves_per_eu(2, 2))) __launch_bounds__(256) void k_attn_fused(
    const u16* __restrict__ Qg, const u16* __restrict__ Kg,
    const u16* __restrict__ Vtg, const float* __restrict__ ebtab,
    u16* __restrict__ ctx, float* __restrict__ AW)
{
  __shared__ bf16_t Ps[4][16*40];          // 5120 B, wave-private
  __shared__ float  invTab[8][16];         // 512 B, one-time exchange

  const int t  = threadIdx.x;
  const int wv = t >> 6;
  const int ln = t & 15;
  const int qd = (t & 63) >> 4;
  const int lane = t & 63;
  const int b  = blockIdx.y;
  const int qt = blockIdx.x;
  const int qh_img = qt >> 1;
  const int qw0 = (qt & 1) * 16;

  const u16* Qb  = Qg  + (size_t)(b*1024 + qt*16) * 256;
  const u16* Kb  = Kg  + (size_t)b * 1024 * 256;
  const u16* Vtb = Vtg + (size_t)b * 256 * 1024;

  f32x4 z4 = {0.0f,0.0f,0.0f,0.0f};

  bf16x8 aq[2];
  aq[0] = *(const bf16x8*)(Qb + ln*256 + wv*32 + qd*8);
  aq[1] = *(const bf16x8*)(Qb + ln*256 + (wv+4)*32 + qd*8);

  float se[2][4], sb[2][4];
  #pragma unroll
  for (int hi=0;hi<2;hi++)
    #pragma unroll
    for (int r=0;r<4;r++){ se[hi][r]=0.0f; sb[hi][r]=0.0f; }

  f32x4 oacc[2][2];
  oacc[0][0]=z4; oacc[0][1]=z4; oacc[1][0]=z4; oacc[1][1]=z4;

  // current-iteration fragments (registers)
  bf16x8 cK[2][2], cV[2][2]; float cE[2];
  #pragma unroll
  for (int hi=0;hi<2;hi++){
    const int h = wv + hi*4;
    #pragma unroll
    for (int kh=0;kh<2;kh++)
      cK[hi][kh] = *(const bf16x8*)(Kb + (size_t)(kh*16 + ln)*256 + h*32 + qd*8);
    #pragma unroll
    for (int nh=0;nh<2;nh++)
      cV[hi][nh] = *(const bf16x8*)(Vtb + (size_t)(h*32 + nh*16 + ln)*1024 + qd*8);
    cE[hi] = ebtab[(size_t)(31 - qh_img)*512 + h*64 + lane];
  }

  // ---- pass 1: exp once -> both denominators + unnormalized PV. No barriers. ----
  #pragma unroll 2
  for (int kt=0; kt<32; kt++){
    bf16x8 nK[2][2], nV[2][2]; float nE[2];
    if (kt < 31){
      #pragma unroll
      for (int hi=0;hi<2;hi++){
        const int h = wv + hi*4;
        #pragma unroll
        for (int kh=0;kh<2;kh++)
          nK[hi][kh] = *(const bf16x8*)(Kb + (size_t)((kt+1)*32 + kh*16 + ln)*256 + h*32 + qd*8);
        #pragma unroll
        for (int nh=0;nh<2;nh++)
          nV[hi][nh] = *(const bf16x8*)(Vtb + (size_t)(h*32 + nh*16 + ln)*1024 + (kt+1)*32 + qd*8);
        nE[hi] = ebtab[(size_t)(kt + 1 - qh_img + 31)*512 + h*64 + lane];
      }
    }

    #pragma unroll
    for (int hi=0;hi<2;hi++){
      #pragma unroll
      for (int kh=0;kh<2;kh++){
        f32x4 sc = MFMA16(aq[hi], cK[hi][kh], z4);
        #pragma unroll
        for (int r=0;r<4;r++){
          float e  = exp2f(sc[r]);                 // Q pre-scaled by log2e/sqrt(dk)
          int idx = kh*16 + ln - (qw0 + qd*4 + r) + 31;   // dw+31 in [0,62]
          float ebv = __shfl(cE[hi], idx);
          float eb = e * ebv;
          se[hi][r] += e;
          sb[hi][r] += eb;
          Ps[wv][(qd*4+r)*40 + kh*16 + ln] = (bf16_t)eb;   // unnormalized
        }
      }
      // per-wave in-order LDS + alias-visible dependence orders Ps write->read;
      // compiler inserts the lgkmcnt wait itself.
      bf16x8 ap = *(const bf16x8*)&Ps[wv][ln*40 + qd*8];
      oacc[hi][0] = MFMA16(ap, cV[hi][0], oacc[hi][0]);
      oacc[hi][1] = MFMA16(ap, cV[hi][1], oacc[hi][1]);
    }

    if (kt < 31){
      #pragma unroll
      for (int hi=0;hi<2;hi++){
        cE[hi] = nE[hi];
        #pragma unroll
        for (int kh=0;kh<2;kh++) cK[hi][kh] = nK[hi][kh];
        #pragma unroll
        for (int nh=0;nh<2;nh++) cV[hi][nh] = nV[hi][nh];
      }
    }
  }

  // reduce denominators across the 16 column-lanes (same qd group)
  float inv_se[2][4], inv_sb[2][4];
  #pragma unroll
  for (int hi=0;hi<2;hi++)
    #pragma unroll
    for (int r=0;r<4;r++){
      float a = se[hi][r], c = sb[hi][r];
      #pragma unroll
      for (int m=1;m<16;m<<=1){ a += __shfl_xor(a, m, 16); c += __shfl_xor(c, m, 16); }
      inv_se[hi][r] = 1.0f / a;
      inv_sb[hi][r] = 1.0f / c;
    }

  // ---- one-time exchange of plain-softmax denominators across waves ----
  if (ln == 0){
    #pragma unroll
    for (int r=0;r<4;r++){
      invTab[wv][qd*4+r]   = inv_se[0][r];
      invTab[wv+4][qd*4+r] = inv_se[1][r];
    }
  }
  __syncthreads();
  float invq[8][4];
  #pragma unroll
  for (int h=0;h<8;h++)
    #pragma unroll
    for (int r=0;r<4;r++)
      invq[h][r] = invTab[h][qd*4+r];

  // Q fragments for all 8 heads (L1/L2-hot re-read; constant-indexed after unroll)
  bf16x8 aqAll[8];
  #pragma unroll
  for (int h=0;h<8;h++)
    aqAll[h] = *(const bf16x8*)(Qb + ln*256 + h*32 + qd*8);

  // ---- pass 2: plain probs -> attn_w (mean over heads). Wave owns kt-range;
  //      head-sum entirely in-register. No barriers. ----
  for (int kti=0; kti<8; kti++){
    const int kt = wv*8 + kti;
    float aw0[2][4];
    #pragma unroll
    for (int kh=0;kh<2;kh++)
      #pragma unroll
      for (int r=0;r<4;r++) aw0[kh][r] = 0.0f;

    #pragma unroll
    for (int h=0;h<8;h++){
      #pragma unroll
      for (int kh=0;kh<2;kh++){
        bf16x8 bk = *(const bf16x8*)(Kb + (size_t)(kt*32 + kh*16 + ln)*256 + h*32 + qd*8);
        f32x4 sc = MFMA16(aqAll[h], bk, z4);
        #pragma unroll
        for (int r=0;r<4;r++)
          aw0[kh][r] += exp2f(sc[r]) * invq[h][r];
      }
    }
    #pragma unroll
    for (int kh=0;kh<2;kh++)
      #pragma unroll
      for (int r=0;r<4;r++)
        AW[(size_t)(b*1024 + qt*16 + qd*4 + r)*1024 + kt*32 + kh*16 + ln]
            = aw0[kh][r] * 0.125f;
  }

  // ---- ctx out (normalize by biased denominator) ----
  #pragma unroll
  for (int hi=0;hi<2;hi++){
    const int h = wv + hi*4;
    #pragma unroll
    for (int nh=0;nh<2;nh++)
      #pragma unroll
      for (int r=0;r<4;r++)
        ctx[(size_t)(b*1024 + qt*16 + qd*4 + r)*256 + h*32 + nh*16 + ln]
            = f2bf(oacc[hi][nh][r] * inv_sb[hi][r]);
  }
}

// ---------------- K3: out = ctx@Wo^T + bo ; y = LN(out + x). f32 out. ---------------------
// 16-row blocks: grid 512 = 2 blocks/CU. Wave wv owns cols [wv*64, wv*64+64).
// Wsh/Ys LDS union -> 22.3KB/block.
__global__ __attribute__((amdgpu_waves_per_eu(2, 2))) __launch_bounds__(256) void k_outln(
    const u16* __restrict__ CX, const float* __restrict__ Wo,
    const float* __restrict__ bo, const float* __restrict__ xs,
    const float* __restrict__ lgm, const float* __restrict__ lbt,
    float* __restrict__ Out)
{
  __shared__ bf16_t Cts[16*40];
  __shared__ __align__(16) char UU[20480];   // union: Wsh bf16[256*40] | Ys f32[16*260]=16640B
  bf16_t* Wsh = (bf16_t*)UU;
  float*  Ys  = (float*)UU;
  __shared__ float  parts[4][16][2];
  const int t = threadIdx.x;
  const int wv = t>>6, ln = t&15, qd = (t&63)>>4;
  const int m0 = blockIdx.x * 16;

  f32x4 z4 = {0.0f,0.0f,0.0f,0.0f};
  f32x4 acc[4];
  #pragma unroll
  for (int i=0;i<4;i++) acc[i] = z4;

  u32 CR; f32x4 WR[8];
  CR = *(const u32*)(CX + (size_t)(m0 + (t>>4))*256 + (t&15)*2);
  #pragma unroll
  for (int j=0;j<8;j++)
    WR[j] = *(const f32x4*)(Wo + (size_t)((t>>3)+32*j)*256 + (t&7)*4);

  for (int kt=0; kt<8; kt++){
    __syncthreads();
    *(u32*)&Cts[(t>>4)*40 + (t&15)*2] = CR;
    #pragma unroll
    for (int j=0;j<8;j++){
      int n = (t>>3) + 32*j, k0 = (t&7)*4;
      uint2 pk; pk.x = pack2(WR[j][0], WR[j][1]); pk.y = pack2(WR[j][2], WR[j][3]);
      *(uint2*)&Wsh[n*40 + k0] = pk;
    }
    __syncthreads();
    if (kt < 7){
      CR = *(const u32*)(CX + (size_t)(m0 + (t>>4))*256 + (kt+1)*32 + (t&15)*2);
      #pragma unroll
      for (int j=0;j<8;j++)
        WR[j] = *(const f32x4*)(Wo + (size_t)((t>>3)+32*j)*256 + (kt+1)*32 + (t&7)*4);
    }
    bf16x8 a = *(const bf16x8*)&Cts[ln*40 + qd*8];
    #pragma unroll
    for (int ni=0;ni<4;ni++){
      bf16x8 bb = *(const bf16x8*)&Wsh[(wv*64 + ni*16 + ln)*40 + qd*8];
      acc[ni] = MFMA16(a, bb, acc[ni]);
    }
  }

  float psum[4]={0,0,0,0}, psq[4]={0,0,0,0};
  #pragma unroll
  for (int ni=0;ni<4;ni++){
    const int col = wv*64 + ni*16 + ln;
    const float bias = bo[col];
    #pragma unroll
    for (int r=0;r<4;r++){
      const int row = qd*4 + r;
      float y = acc[ni][r] + bias + xs[(size_t)(m0+row)*256 + col];
      acc[ni][r] = y;
      psum[r] += y; psq[r] += y*y;
    }
  }
  #pragma unroll
  for (int r=0;r<4;r++){
    float a1 = psum[r], a2 = psq[r];
    #pragma unroll
    for (int m=1;m<16;m<<=1){ a1 += __shfl_xor(a1,m,16); a2 += __shfl_xor(a2,m,16); }
    if (ln == 0){
      parts[wv][qd*4 + r][0] = a1;
      parts[wv][qd*4 + r][1] = a2;
    }
  }
  __syncthreads();   // also: all Wsh reads done -> Ys may take over the union
  #pragma unroll
  for (int r=0;r<4;r++){
    const int row = qd*4 + r;
    float s1 = parts[0][row][0] + parts[1][row][0] + parts[2][row][0] + parts[3][row][0];
    float s2 = parts[0][row][1] + parts[1][row][1] + parts[2][row][1] + parts[3][row][1];
    float mu  = s1 * 0.00390625f;
    float var = s2 * 0.00390625f - mu*mu;
    float rs = rsqrtf(var + 1e-5f);
    #pragma unroll
    for (int ni=0;ni<4;ni++){
      const int col = wv*64 + ni*16 + ln;
      Ys[row*260 + col] = (acc[ni][r] - mu)*rs*lgm[col] + lbt[col];
    }
  }
  __syncthreads();
  { int row = t>>4, c0 = (t&15)*16;
    float* op = Out + (size_t)(m0+row)*256 + c0;
    #pragma unroll
    for (int i=0;i<4;i++)
      *(f32x4*)(op + 4*i) = *(const f32x4*)&Ys[row*260 + c0 + 4*i];
  }
}

// -----------------------------------------------------------------------------------------
extern "C" void kernel_launch(void* const* d_in, const int* in_sizes, int n_in,
                              void* d_out, int out_size, void* d_ws, size_t ws_size,
                              hipStream_t stream)
{
  const float* x   = (const float*)d_in[0];
  const float* wq  = (const float*)d_in[1];
  const float* bq  = (const float*)d_in[2];
  const float* wk  = (const float*)d_in[3];
  const float* bk  = (const float*)d_in[4];
  const float* wv_ = (const float*)d_in[5];
  const float* bv  = (const float*)d_in[6];
  const float* wo  = (const float*)d_in[7];
  const float* bo  = (const float*)d_in[8];
  const float* lng = (const float*)d_in[9];
  const float* lnb = (const float*)d_in[10];
  const float* dib = (const float*)d_in[11];
  const float* drb = (const float*)d_in[12];

  // ws: ebtab 128K | CX bf16 4MB | Vt bf16 4MB = 8.5 MB.
  // d_out f32: y [0, 8MB) ; attn_w [8MB, 41.5MB).
  //   Q bf16 at y [0,4M), K bf16 at y [4M,8M) -> dead before k_outln writes y (serial).
  char*  ws    = (char*)d_ws;
  float* ebtab = (float*)ws;
  u16*   CX    = (u16*)(ws + 131072);
  u16*   Vt    = (u16*)(ws + 131072 + 4194304);
  float* y     = (float*)d_out;
  float* aw    = y + 2097152;
  u16*   Q     = (u16*)y;
  u16*   K     = (u16*)((char*)y + 4194304);

  const float qscale = 0.25503486f;   // log2(e)/sqrt(32) folded into Q

  k_proj3b<<<dim3(256, 4), 256, 0, stream>>>(x, wq, bq, wk, bk, wv_, bv, Q, K, Vt,
                                             qscale, dib, drb, ebtab);
  k_attn_fused<<<dim3(64, 8), 256, 0, stream>>>(Q, K, Vt, ebtab, CX, aw);
  k_outln<<<512, 256, 0, stream>>>(CX, wo, bo, x, lng, lnb, y);
}

// Round 15
// 213.670 us; speedup vs baseline: 1.0620x; 1.0141x over previous
//
#include <hip/hip_runtime.h>
#include <stdint.h>

typedef uint16_t u16;
typedef uint32_t u32;
typedef __bf16 bf16_t;
typedef __bf16 bf16x8 __attribute__((ext_vector_type(8)));
typedef float  f32x4  __attribute__((ext_vector_type(4)));

#define MFMA16(a,b,c) __builtin_amdgcn_mfma_f32_16x16x32_bf16(a,b,c,0,0,0)

static __device__ __forceinline__ u16 f2bf(float f){
  union { bf16_t b; u16 u; } cv; cv.b = (bf16_t)f; return cv.u;
}
static __device__ __forceinline__ u32 pack2(float a, float b){
  return (u32)f2bf(a) | ((u32)f2bf(b) << 16);
}

// ---------------- K1: fused Q/K/V projection + (y==3) bias-table blocks. ------------------
// C[8192,256] = X @ W^T + b (f32 in, bf16 MFMA, bf16 out), reg-prefetch double-buffered.
// Wsh/Cs union keeps LDS at 35.8KB. (4,4): 4 blocks/CU co-resident -> the 1024-block
// grid runs in ONE dispatch round (with (3,3) it was 768+256 = two rounds, 33% tail).
// LDS 35.8KB x 4 = 143KB < 160KB; est ~100 VGPR <= 128 budget (WRITE_SIZE is the
// no-spill mechanism check).
__global__ __attribute__((amdgpu_waves_per_eu(4, 4))) __launch_bounds__(256) void k_proj3b(
    const float* __restrict__ X,
    const float* __restrict__ Wq, const float* __restrict__ Bq,
    const float* __restrict__ Wk, const float* __restrict__ Bk,
    const float* __restrict__ Wv, const float* __restrict__ Bvv,
    u16* __restrict__ Qo, u16* __restrict__ Ko, u16* __restrict__ Vo,
    float qscale,
    const float* __restrict__ dist_bias, const float* __restrict__ dir_bias,
    float* __restrict__ ebtab)
{
  if (blockIdx.y == 3){
    int tid = blockIdx.x*256 + threadIdx.x;
    if (blockIdx.x >= 16 || tid >= 63*63) return;
    int dhi = tid / 63, dwi = tid % 63;
    int dh = dhi - 31, dw = dwi - 31;
    int dist = (int)sqrtf((float)(dh*dh + dw*dw));
    if (dist > 59) dist = 59;
    int dir;
    if (dh==0 && dw==0)      dir = 0;
    else if (dh==0)          dir = (dw>0) ? 8  : 0;
    else if (dw==0)          dir = (dh>0) ? 12 : 4;
    else if (dh==dw)         dir = (dh>0) ? 10 : 2;
    else if (dh==-dw)        dir = (dh>0) ? 14 : 6;
    else {
      float ang = atan2f((float)dh, (float)dw) + 3.14159265358979323846f;
      int k = (int)floorf(ang * 2.5464790894703254f);
      dir = k & 15;
    }
    for (int h=0; h<8; h++){
      ebtab[dhi*512 + h*64 + dwi] = expf(dist_bias[dist*8+h] + dir_bias[dir*8+h]);
    }
    return;
  }

  const float* W; const float* Bv; u16* Out; float scale; int vt_mode;
  if (blockIdx.y == 0)      { W = Wq; Bv = Bq;  Out = Qo; scale = qscale; vt_mode = 0; }
  else if (blockIdx.y == 1) { W = Wk; Bv = Bk;  Out = Ko; scale = 1.0f;   vt_mode = 0; }
  else                      { W = Wv; Bv = Bvv; Out = Vo; scale = 1.0f;   vt_mode = 1; }

  __shared__ bf16_t Xs[32*40];
  __shared__ __align__(16) char UU[33280];   // union: Wsh bf16[256*40]=20480B | Cs f32[32*260]=33280B
  bf16_t* Wsh = (bf16_t*)UU;
  float*  Cs  = (float*)UU;
  const int t = threadIdx.x;
  const int wv = t>>6, ln = t&15, qd = (t&63)>>4;
  const int wm = wv & 1, wn = wv >> 1;
  const int m0 = blockIdx.x * 32;

  f32x4 z4 = {0.0f,0.0f,0.0f,0.0f};
  f32x4 acc[8];
  #pragma unroll
  for (int i=0;i<8;i++) acc[i] = z4;

  f32x4 XR; f32x4 WR[8];
  XR = *(const f32x4*)(X + (size_t)(m0 + (t>>3))*256 + (t&7)*4);
  #pragma unroll
  for (int j=0;j<8;j++)
    WR[j] = *(const f32x4*)(W + (size_t)((t>>3)+32*j)*256 + (t&7)*4);

  for (int kt=0; kt<8; kt++){
    __syncthreads();
    { int m = t>>3, k0 = (t&7)*4;
      uint2 pk; pk.x = pack2(XR[0], XR[1]); pk.y = pack2(XR[2], XR[3]);
      *(uint2*)&Xs[m*40 + k0] = pk;
    }
    #pragma unroll
    for (int j=0;j<8;j++){
      int n = (t>>3) + 32*j, k0 = (t&7)*4;
      uint2 pk; pk.x = pack2(WR[j][0], WR[j][1]); pk.y = pack2(WR[j][2], WR[j][3]);
      *(uint2*)&Wsh[n*40 + k0] = pk;
    }
    __syncthreads();
    if (kt < 7){
      XR = *(const f32x4*)(X + (size_t)(m0 + (t>>3))*256 + (kt+1)*32 + (t&7)*4);
      #pragma unroll
      for (int j=0;j<8;j++)
        WR[j] = *(const f32x4*)(W + (size_t)((t>>3)+32*j)*256 + (kt+1)*32 + (t&7)*4);
    }
    bf16x8 a = *(const bf16x8*)&Xs[(wm*16+ln)*40 + qd*8];
    #pragma unroll
    for (int ni=0;ni<8;ni++){
      bf16x8 bb = *(const bf16x8*)&Wsh[(wn*128 + ni*16 + ln)*40 + qd*8];
      acc[ni] = MFMA16(a, bb, acc[ni]);
    }
  }
  __syncthreads();   // Wsh dead after this point; Cs takes over the union
  #pragma unroll
  for (int ni=0;ni<8;ni++){
    const int col = wn*128 + ni*16 + ln;
    const float bias = Bv[col];
    #pragma unroll
    for (int r=0;r<4;r++){
      Cs[(wm*16 + qd*4 + r)*260 + col] = (acc[ni][r] + bias) * scale;
    }
  }
  __syncthreads();
  if (!vt_mode){
    int row = t>>3, c0 = (t&7)*32;
    u16* op = Out + (size_t)(m0+row)*256 + c0;
    #pragma unroll
    for (int i=0;i<4;i++){
      f32x4 v0 = *(const f32x4*)&Cs[row*260 + c0 + i*8];
      f32x4 v1 = *(const f32x4*)&Cs[row*260 + c0 + i*8 + 4];
      union { u16 h[8]; uint4 v; } pk;
      #pragma unroll
      for (int e=0;e<4;e++){ pk.h[e] = f2bf(v0[e]); pk.h[4+e] = f2bf(v1[e]); }
      *(uint4*)(op + i*8) = pk.v;
    }
  } else {
    const int n = t;
    const int b = m0 >> 10, s0 = m0 & 1023;
    u16* op = Out + (size_t)(b*256 + n)*1024 + s0;
    #pragma unroll
    for (int i=0;i<4;i++){
      union { u16 h[8]; uint4 v; } pk;
      #pragma unroll
      for (int e=0;e<8;e++) pk.h[e] = f2bf(Cs[(i*8+e)*260 + n]);
      *(uint4*)(op + i*8) = pk.v;
    }
  }
}

// ---------------- K2: fused attention (r5 structure; XCD batch-affinity swizzle). ---------
// GRID CHANGE (T1): dim3(8, 64) with b = blockIdx.x, qt = blockIdx.y. Linear block id
// = b + 8*qt -> round-robin XCD assignment puts ALL 64 blocks of batch b on XCD b, so
// the batch's 1.5MB Q/K/V working set stays hot in that XCD's 4MB L2. r14 counters:
// FETCH 52.4MB vs 12.5MB intrinsic = L2 capacity misses (old grid mixed all 8 batches
// = 12MB onto every XCD). For this latency-bound kernel (all pipes <33%), L3->L2
// latency is the critical path; FETCH_SIZE collapse is the mechanism check.
__global__ __attribute__((amdgpu_waves_per_eu(2, 2))) __launch_bounds__(256) void k_attn_fused(
    const u16* __restrict__ Qg, const u16* __restrict__ Kg,
    const u16* __restrict__ Vtg, const float* __restrict__ ebtab,
    u16* __restrict__ ctx, float* __restrict__ AW)
{
  __shared__ bf16_t Ps[4][16*40];          // 5120 B, wave-private
  __shared__ float  invTab[8][16];         // 512 B, one-time exchange

  const int t  = threadIdx.x;
  const int wv = t >> 6;
  const int ln = t & 15;
  const int qd = (t & 63) >> 4;
  const int lane = t & 63;
  const int b  = blockIdx.x;               // batch -> XCD (linear%8 == x)
  const int qt = blockIdx.y;
  const int qh_img = qt >> 1;
  const int qw0 = (qt & 1) * 16;

  const u16* Qb  = Qg  + (size_t)(b*1024 + qt*16) * 256;
  const u16* Kb  = Kg  + (size_t)b * 1024 * 256;
  const u16* Vtb = Vtg + (size_t)b * 256 * 1024;

  f32x4 z4 = {0.0f,0.0f,0.0f,0.0f};

  bf16x8 aq[2];
  aq[0] = *(const bf16x8*)(Qb + ln*256 + wv*32 + qd*8);
  aq[1] = *(const bf16x8*)(Qb + ln*256 + (wv+4)*32 + qd*8);

  float se[2][4], sb[2][4];
  #pragma unroll
  for (int hi=0;hi<2;hi++)
    #pragma unroll
    for (int r=0;r<4;r++){ se[hi][r]=0.0f; sb[hi][r]=0.0f; }

  f32x4 oacc[2][2];
  oacc[0][0]=z4; oacc[0][1]=z4; oacc[1][0]=z4; oacc[1][1]=z4;

  // current-iteration fragments (registers)
  bf16x8 cK[2][2], cV[2][2]; float cE[2];
  #pragma unroll
  for (int hi=0;hi<2;hi++){
    const int h = wv + hi*4;
    #pragma unroll
    for (int kh=0;kh<2;kh++)
      cK[hi][kh] = *(const bf16x8*)(Kb + (size_t)(kh*16 + ln)*256 + h*32 + qd*8);
    #pragma unroll
    for (int nh=0;nh<2;nh++)
      cV[hi][nh] = *(const bf16x8*)(Vtb + (size_t)(h*32 + nh*16 + ln)*1024 + qd*8);
    cE[hi] = ebtab[(size_t)(31 - qh_img)*512 + h*64 + lane];
  }

  // ---- pass 1: exp once -> both denominators + unnormalized PV. No barriers. ----
  #pragma unroll 2
  for (int kt=0; kt<32; kt++){
    bf16x8 nK[2][2], nV[2][2]; float nE[2];
    if (kt < 31){
      #pragma unroll
      for (int hi=0;hi<2;hi++){
        const int h = wv + hi*4;
        #pragma unroll
        for (int kh=0;kh<2;kh++)
          nK[hi][kh] = *(const bf16x8*)(Kb + (size_t)((kt+1)*32 + kh*16 + ln)*256 + h*32 + qd*8);
        #pragma unroll
        for (int nh=0;nh<2;nh++)
          nV[hi][nh] = *(const bf16x8*)(Vtb + (size_t)(h*32 + nh*16 + ln)*1024 + (kt+1)*32 + qd*8);
        nE[hi] = ebtab[(size_t)(kt + 1 - qh_img + 31)*512 + h*64 + lane];
      }
    }

    #pragma unroll
    for (int hi=0;hi<2;hi++){
      #pragma unroll
      for (int kh=0;kh<2;kh++){
        f32x4 sc = MFMA16(aq[hi], cK[hi][kh], z4);
        #pragma unroll
        for (int r=0;r<4;r++){
          float e  = exp2f(sc[r]);                 // Q pre-scaled by log2e/sqrt(dk)
          int idx = kh*16 + ln - (qw0 + qd*4 + r) + 31;   // dw+31 in [0,62]
          float ebv = __shfl(cE[hi], idx);
          float eb = e * ebv;
          se[hi][r] += e;
          sb[hi][r] += eb;
          Ps[wv][(qd*4+r)*40 + kh*16 + ln] = (bf16_t)eb;   // unnormalized
        }
      }
      // per-wave in-order LDS + alias-visible dependence orders Ps write->read;
      // compiler inserts the lgkmcnt wait itself.
      bf16x8 ap = *(const bf16x8*)&Ps[wv][ln*40 + qd*8];
      oacc[hi][0] = MFMA16(ap, cV[hi][0], oacc[hi][0]);
      oacc[hi][1] = MFMA16(ap, cV[hi][1], oacc[hi][1]);
    }

    if (kt < 31){
      #pragma unroll
      for (int hi=0;hi<2;hi++){
        cE[hi] = nE[hi];
        #pragma unroll
        for (int kh=0;kh<2;kh++) cK[hi][kh] = nK[hi][kh];
        #pragma unroll
        for (int nh=0;nh<2;nh++) cV[hi][nh] = nV[hi][nh];
      }
    }
  }

  // reduce denominators across the 16 column-lanes (same qd group)
  float inv_se[2][4], inv_sb[2][4];
  #pragma unroll
  for (int hi=0;hi<2;hi++)
    #pragma unroll
    for (int r=0;r<4;r++){
      float a = se[hi][r], c = sb[hi][r];
      #pragma unroll
      for (int m=1;m<16;m<<=1){ a += __shfl_xor(a, m, 16); c += __shfl_xor(c, m, 16); }
      inv_se[hi][r] = 1.0f / a;
      inv_sb[hi][r] = 1.0f / c;
    }

  // ---- one-time exchange of plain-softmax denominators across waves ----
  if (ln == 0){
    #pragma unroll
    for (int r=0;r<4;r++){
      invTab[wv][qd*4+r]   = inv_se[0][r];
      invTab[wv+4][qd*4+r] = inv_se[1][r];
    }
  }
  __syncthreads();
  float invq[8][4];
  #pragma unroll
  for (int h=0;h<8;h++)
    #pragma unroll
    for (int r=0;r<4;r++)
      invq[h][r] = invTab[h][qd*4+r];

  // Q fragments for all 8 heads (L1/L2-hot re-read; constant-indexed after unroll)
  bf16x8 aqAll[8];
  #pragma unroll
  for (int h=0;h<8;h++)
    aqAll[h] = *(const bf16x8*)(Qb + ln*256 + h*32 + qd*8);

  // ---- pass 2: plain probs -> attn_w (mean over heads). Wave owns kt-range;
  //      head-sum entirely in-register. No barriers. ----
  for (int kti=0; kti<8; kti++){
    const int kt = wv*8 + kti;
    float aw0[2][4];
    #pragma unroll
    for (int kh=0;kh<2;kh++)
      #pragma unroll
      for (int r=0;r<4;r++) aw0[kh][r] = 0.0f;

    #pragma unroll
    for (int h=0;h<8;h++){
      #pragma unroll
      for (int kh=0;kh<2;kh++){
        bf16x8 bk = *(const bf16x8*)(Kb + (size_t)(kt*32 + kh*16 + ln)*256 + h*32 + qd*8);
        f32x4 sc = MFMA16(aqAll[h], bk, z4);
        #pragma unroll
        for (int r=0;r<4;r++)
          aw0[kh][r] += exp2f(sc[r]) * invq[h][r];
      }
    }
    #pragma unroll
    for (int kh=0;kh<2;kh++)
      #pragma unroll
      for (int r=0;r<4;r++)
        AW[(size_t)(b*1024 + qt*16 + qd*4 + r)*1024 + kt*32 + kh*16 + ln]
            = aw0[kh][r] * 0.125f;
  }

  // ---- ctx out (normalize by biased denominator) ----
  #pragma unroll
  for (int hi=0;hi<2;hi++){
    const int h = wv + hi*4;
    #pragma unroll
    for (int nh=0;nh<2;nh++)
      #pragma unroll
      for (int r=0;r<4;r++)
        ctx[(size_t)(b*1024 + qt*16 + qd*4 + r)*256 + h*32 + nh*16 + ln]
            = f2bf(oacc[hi][nh][r] * inv_sb[hi][r]);
  }
}

// ---------------- K3: out = ctx@Wo^T + bo ; y = LN(out + x). f32 out. ---------------------
// 16-row blocks: grid 512 = 2 blocks/CU. Wave wv owns cols [wv*64, wv*64+64).
// Wsh/Ys LDS union -> 22.3KB/block.
__global__ __attribute__((amdgpu_waves_per_eu(2, 2))) __launch_bounds__(256) void k_outln(
    const u16* __restrict__ CX, const float* __restrict__ Wo,
    const float* __restrict__ bo, const float* __restrict__ xs,
    const float* __restrict__ lgm, const float* __restrict__ lbt,
    float* __restrict__ Out)
{
  __shared__ bf16_t Cts[16*40];
  __shared__ __align__(16) char UU[20480];   // union: Wsh bf16[256*40] | Ys f32[16*260]=16640B
  bf16_t* Wsh = (bf16_t*)UU;
  float*  Ys  = (float*)UU;
  __shared__ float  parts[4][16][2];
  const int t = threadIdx.x;
  const int wv = t>>6, ln = t&15, qd = (t&63)>>4;
  const int m0 = blockIdx.x * 16;

  f32x4 z4 = {0.0f,0.0f,0.0f,0.0f};
  f32x4 acc[4];
  #pragma unroll
  for (int i=0;i<4;i++) acc[i] = z4;

  u32 CR; f32x4 WR[8];
  CR = *(const u32*)(CX + (size_t)(m0 + (t>>4))*256 + (t&15)*2);
  #pragma unroll
  for (int j=0;j<8;j++)
    WR[j] = *(const f32x4*)(Wo + (size_t)((t>>3)+32*j)*256 + (t&7)*4);

  for (int kt=0; kt<8; kt++){
    __syncthreads();
    *(u32*)&Cts[(t>>4)*40 + (t&15)*2] = CR;
    #pragma unroll
    for (int j=0;j<8;j++){
      int n = (t>>3) + 32*j, k0 = (t&7)*4;
      uint2 pk; pk.x = pack2(WR[j][0], WR[j][1]); pk.y = pack2(WR[j][2], WR[j][3]);
      *(uint2*)&Wsh[n*40 + k0] = pk;
    }
    __syncthreads();
    if (kt < 7){
      CR = *(const u32*)(CX + (size_t)(m0 + (t>>4))*256 + (kt+1)*32 + (t&15)*2);
      #pragma unroll
      for (int j=0;j<8;j++)
        WR[j] = *(const f32x4*)(Wo + (size_t)((t>>3)+32*j)*256 + (kt+1)*32 + (t&7)*4);
    }
    bf16x8 a = *(const bf16x8*)&Cts[ln*40 + qd*8];
    #pragma unroll
    for (int ni=0;ni<4;ni++){
      bf16x8 bb = *(const bf16x8*)&Wsh[(wv*64 + ni*16 + ln)*40 + qd*8];
      acc[ni] = MFMA16(a, bb, acc[ni]);
    }
  }

  float psum[4]={0,0,0,0}, psq[4]={0,0,0,0};
  #pragma unroll
  for (int ni=0;ni<4;ni++){
    const int col = wv*64 + ni*16 + ln;
    const float bias = bo[col];
    #pragma unroll
    for (int r=0;r<4;r++){
      const int row = qd*4 + r;
      float y = acc[ni][r] + bias + xs[(size_t)(m0+row)*256 + col];
      acc[ni][r] = y;
      psum[r] += y; psq[r] += y*y;
    }
  }
  #pragma unroll
  for (int r=0;r<4;r++){
    float a1 = psum[r], a2 = psq[r];
    #pragma unroll
    for (int m=1;m<16;m<<=1){ a1 += __shfl_xor(a1,m,16); a2 += __shfl_xor(a2,m,16); }
    if (ln == 0){
      parts[wv][qd*4 + r][0] = a1;
      parts[wv][qd*4 + r][1] = a2;
    }
  }
  __syncthreads();   // also: all Wsh reads done -> Ys may take over the union
  #pragma unroll
  for (int r=0;r<4;r++){
    const int row = qd*4 + r;
    float s1 = parts[0][row][0] + parts[1][row][0] + parts[2][row][0] + parts[3][row][0];
    float s2 = parts[0][row][1] + parts[1][row][1] + parts[2][row][1] + parts[3][row][1];
    float mu  = s1 * 0.00390625f;
    float var = s2 * 0.00390625f - mu*mu;
    float rs = rsqrtf(var + 1e-5f);
    #pragma unroll
    for (int ni=0;ni<4;ni++){
      const int col = wv*64 + ni*16 + ln;
      Ys[row*260 + col] = (acc[ni][r] - mu)*rs*lgm[col] + lbt[col];
    }
  }
  __syncthreads();
  { int row = t>>4, c0 = (t&15)*16;
    float* op = Out + (size_t)(m0+row)*256 + c0;
    #pragma unroll
    for (int i=0;i<4;i++)
      *(f32x4*)(op + 4*i) = *(const f32x4*)&Ys[row*260 + c0 + 4*i];
  }
}

// -----------------------------------------------------------------------------------------
extern "C" void kernel_launch(void* const* d_in, const int* in_sizes, int n_in,
                              void* d_out, int out_size, void* d_ws, size_t ws_size,
                              hipStream_t stream)
{
  const float* x   = (const float*)d_in[0];
  const float* wq  = (const float*)d_in[1];
  const float* bq  = (const float*)d_in[2];
  const float* wk  = (const float*)d_in[3];
  const float* bk  = (const float*)d_in[4];
  const float* wv_ = (const float*)d_in[5];
  const float* bv  = (const float*)d_in[6];
  const float* wo  = (const float*)d_in[7];
  const float* bo  = (const float*)d_in[8];
  const float* lng = (const float*)d_in[9];
  const float* lnb = (const float*)d_in[10];
  const float* dib = (const float*)d_in[11];
  const float* drb = (const float*)d_in[12];

  // ws: ebtab 128K | CX bf16 4MB | Vt bf16 4MB = 8.5 MB.
  // d_out f32: y [0, 8MB) ; attn_w [8MB, 41.5MB).
  //   Q bf16 at y [0,4M), K bf16 at y [4M,8M) -> dead before k_outln writes y (serial).
  char*  ws    = (char*)d_ws;
  float* ebtab = (float*)ws;
  u16*   CX    = (u16*)(ws + 131072);
  u16*   Vt    = (u16*)(ws + 131072 + 4194304);
  float* y     = (float*)d_out;
  float* aw    = y + 2097152;
  u16*   Q     = (u16*)y;
  u16*   K     = (u16*)((char*)y + 4194304);

  const float qscale = 0.25503486f;   // log2(e)/sqrt(32) folded into Q

  k_proj3b<<<dim3(256, 4), 256, 0, stream>>>(x, wq, bq, wk, bk, wv_, bv, Q, K, Vt,
                                             qscale, dib, drb, ebtab);
  k_attn_fused<<<dim3(8, 64), 256, 0, stream>>>(Q, K, Vt, ebtab, CX, aw);
  k_outln<<<512, 256, 0, stream>>>(CX, wo, bo, x, lng, lnb, y);
}